// Round 2
// baseline (8699.386 us; speedup 1.0000x reference)
//
#include <hip/hip_runtime.h>
#include <math.h>

// ---------------------------------------------------------------------------
// MLA forward, fp32 baseline, TOKEN-CHUNKED so scratch fits in ws_size.
// Per chunk of Tc tokens (Tc divides 16384, chosen so Tc*9792*4B <= ws_size):
//   G1: tmpA = x_c @ wq_a          (Tc x 2048 x 1536)
//   rmsnorm(tmpA, q_norm_w)
//   G2: q = tmpA @ wq_b            (Tc x 1536 x 3072)
//   rope on q[..., 128:192], pos = ((global_s*16+h) % 4096) + start_pos
//   G3: kv = x_c @ wkv_a           (Tc x 2048 x 576)
//   rope on k_pe = kv[..., 512:576], pos = start_pos
//   rmsnorm(kv[..., :512], ones) (stride 576)
//   G4: kvup = kvn @ wkv_b         (Tc x 512 x 4096)
//   attention per token -> ctx (reuses tmpA slot)
//   G5: out_c = ctx @ wo           (Tc x 2048 x 2048)
// ---------------------------------------------------------------------------

#define GEMM_BM 64
#define GEMM_BN 64
#define GEMM_BK 16

// A: M x K row-major with leading dim lda; B: K x N row-major; C: M x N (ld N).
// Requires M % 64 == 0, N % 64 == 0, K % 16 == 0.
__global__ __launch_bounds__(256) void gemm_f32(
    const float* __restrict__ A, const float* __restrict__ B,
    float* __restrict__ C, int M, int N, int K, int lda) {
  __shared__ float As[GEMM_BK][GEMM_BM];
  __shared__ float Bs[GEMM_BK][GEMM_BN];
  const int tid = threadIdx.x;
  const int bx = blockIdx.x;  // N tile
  const int by = blockIdx.y;  // M tile
  const int tx = tid & 15;
  const int ty = tid >> 4;

  float acc[4][4] = {};
  const float* Ab = A + (size_t)by * 64 * lda;
  const float* Bb = B + (size_t)bx * 64;

  for (int kt = 0; kt < K; kt += GEMM_BK) {
#pragma unroll
    for (int i = 0; i < 4; i++) {
      int idx = tid + i * 256;
      int r = idx >> 4, c = idx & 15;
      As[c][r] = Ab[(size_t)r * lda + kt + c];
    }
#pragma unroll
    for (int i = 0; i < 4; i++) {
      int idx = tid + i * 256;
      int r = idx >> 6, c = idx & 63;
      Bs[r][c] = Bb[(size_t)(kt + r) * N + c];
    }
    __syncthreads();
#pragma unroll
    for (int k = 0; k < GEMM_BK; k++) {
      float a[4], b[4];
#pragma unroll
      for (int i = 0; i < 4; i++) a[i] = As[k][ty * 4 + i];
#pragma unroll
      for (int j = 0; j < 4; j++) b[j] = Bs[k][tx * 4 + j];
#pragma unroll
      for (int i = 0; i < 4; i++)
#pragma unroll
        for (int j = 0; j < 4; j++) acc[i][j] += a[i] * b[j];
    }
    __syncthreads();
  }
#pragma unroll
  for (int i = 0; i < 4; i++) {
    size_t row = (size_t)by * 64 + ty * 4 + i;
#pragma unroll
    for (int j = 0; j < 4; j++)
      C[row * N + bx * 64 + tx * 4 + j] = acc[i][j];
  }
}

// In-place RMSNorm over rows. w == nullptr means weight of ones.
__global__ __launch_bounds__(256) void rmsnorm_inplace(
    float* __restrict__ x, const float* __restrict__ w, int ncols, int stride) {
  float* xr = x + (size_t)blockIdx.x * stride;
  float ss = 0.f;
  for (int c = threadIdx.x; c < ncols; c += 256) {
    float v = xr[c];
    ss += v * v;
  }
#pragma unroll
  for (int off = 32; off > 0; off >>= 1) ss += __shfl_down(ss, off);
  __shared__ float wsum[4];
  __shared__ float scale_sh;
  int wave = threadIdx.x >> 6, lane = threadIdx.x & 63;
  if (lane == 0) wsum[wave] = ss;
  __syncthreads();
  if (threadIdx.x == 0) {
    float tot = wsum[0] + wsum[1] + wsum[2] + wsum[3];
    scale_sh = rsqrtf(tot / (float)ncols + 1e-6f);
  }
  __syncthreads();
  float scale = scale_sh;
  for (int c = threadIdx.x; c < ncols; c += 256) {
    float v = xr[c] * scale;
    if (w) v *= w[c];
    xr[c] = v;
  }
}

// RoPE on q[..., 128:192] for each (local token, head). t0 = chunk start token.
// Bug-compatible position: reference reshapes (b,s,h,dr)->(b,h,s,dr) without
// transpose, so pos = ((global_s*16 + h) % 4096) + start_pos, global_s =
// (t0 + t) % 4096.
__global__ __launch_bounds__(256) void rope_q(
    float* __restrict__ q, const int* __restrict__ start_pos_p, int t0) {
  int idx = blockIdx.x * 256 + threadIdx.x;  // Tc*16*32 total
  int i = idx & 31;
  int th = idx >> 5;
  int t = th >> 4;
  int h = th & 15;
  int s_idx = (t0 + t) & 4095;
  int pos = ((s_idx * 16 + h) & 4095) + start_pos_p[0];
  double theta = pow(10000.0, -(double)i / 32.0);
  double ang = (double)pos * theta;
  float c = (float)cos(ang), s = (float)sin(ang);
  float* base = q + (size_t)t * 3072 + h * 192 + 128;
  float x1 = base[i], x2 = base[i + 32];
  base[i] = x1 * c - x2 * s;
  base[i + 32] = x2 * c + x1 * s;
}

// RoPE on k_pe = kv[..., 512:576]; reference applies it with seq_len==1, so
// pos = start_pos for every token (identity when start_pos==0).
__global__ __launch_bounds__(256) void rope_kpe(
    float* __restrict__ kv, const int* __restrict__ start_pos_p) {
  int idx = blockIdx.x * 256 + threadIdx.x;  // Tc*32 total
  int i = idx & 31;
  int t = idx >> 5;
  int pos = start_pos_p[0];
  double theta = pow(10000.0, -(double)i / 32.0);
  double ang = (double)pos * theta;
  float c = (float)cos(ang), s = (float)sin(ang);
  float* base = kv + (size_t)t * 576 + 512;
  float x1 = base[i], x2 = base[i + 32];
  base[i] = x1 * c - x2 * s;
  base[i + 32] = x2 * c + x1 * s;
}

// Per-token head-vs-head attention (einsum 'bsqd,bskd->bsqk' is over the 16
// heads at the SAME position). One block per token.
__global__ __launch_bounds__(256) void attn_per_token(
    const float* __restrict__ q,     // [Tc][16][192]
    const float* __restrict__ kvup,  // [Tc][16][256] = (k_nope | v)
    const float* __restrict__ kv,    // [Tc][576], k_pe at +512
    float* __restrict__ ctx) {       // [Tc][16][128]
  int t = blockIdx.x;
  __shared__ float sq[16 * 192];
  __shared__ float sk[16 * 128];
  __shared__ float skpe[64];
  __shared__ float sv[16 * 128];
  __shared__ float sc[16][16];
  __shared__ float sprob[16][16];
  int tid = threadIdx.x;
  const float* qb = q + (size_t)t * 3072;
  const float* ub = kvup + (size_t)t * 4096;
  for (int i = tid; i < 3072; i += 256) sq[i] = qb[i];
  for (int i = tid; i < 2048; i += 256) {
    int hh = i >> 7, d = i & 127;
    sk[i] = ub[hh * 256 + d];
    sv[i] = ub[hh * 256 + 128 + d];
  }
  if (tid < 64) skpe[tid] = kv[(size_t)t * 576 + 512 + tid];
  __syncthreads();

  int qh = tid >> 4, kh = tid & 15;
  const float* qq = sq + qh * 192;
  const float* kk = sk + kh * 128;
  float acc = 0.f;
#pragma unroll 4
  for (int d = 0; d < 128; d++) acc += qq[d] * kk[d];
#pragma unroll 4
  for (int d = 0; d < 64; d++) acc += qq[128 + d] * skpe[d];
  sc[qh][kh] = acc * 0.07216878364870323f;  // 1/sqrt(192)
  __syncthreads();

  if (tid < 16) {
    float m = sc[tid][0];
#pragma unroll
    for (int j = 1; j < 16; j++) m = fmaxf(m, sc[tid][j]);
    float e[16], ssum = 0.f;
#pragma unroll
    for (int j = 0; j < 16; j++) {
      e[j] = expf(sc[tid][j] - m);
      ssum += e[j];
    }
    float inv = 1.0f / ssum;
#pragma unroll
    for (int j = 0; j < 16; j++) sprob[tid][j] = e[j] * inv;
  }
  __syncthreads();

  float* cb = ctx + (size_t)t * 2048;
  for (int o = tid; o < 2048; o += 256) {
    int hh = o >> 7, d = o & 127;
    float a = 0.f;
#pragma unroll
    for (int j = 0; j < 16; j++) a += sprob[hh][j] * sv[j * 128 + d];
    cb[o] = a;
  }
}

extern "C" void kernel_launch(void* const* d_in, const int* in_sizes, int n_in,
                              void* d_out, int out_size, void* d_ws,
                              size_t ws_size, hipStream_t stream) {
  const float* x = (const float*)d_in[0];          // 4*4096*2048
  const float* wq_a = (const float*)d_in[1];       // 2048*1536
  const float* q_norm_w = (const float*)d_in[2];   // 1536
  const float* wq_b = (const float*)d_in[3];       // 1536*3072
  const float* wkv_a = (const float*)d_in[4];      // 2048*576
  const float* wkv_b = (const float*)d_in[5];      // 512*4096
  const float* wo = (const float*)d_in[6];         // 2048*2048
  const int* start_pos = (const int*)d_in[7];      // scalar
  float* out = (float*)d_out;

  const int T = 16384;  // b*s = 4*4096
  // Per-token scratch: q(3072) + kvup(4096) + ctx/tmpA(2048) + kv(576)
  const size_t per_tok = 9792 * sizeof(float);
  int Tc = T;
  while (Tc > 64 && (size_t)Tc * per_tok > ws_size) Tc >>= 1;

  float* ws = (float*)d_ws;
  float* q_buf = ws;                              // Tc*3072
  float* kvup = q_buf + (size_t)Tc * 3072;        // Tc*4096
  float* cbuf = kvup + (size_t)Tc * 4096;         // Tc*2048 (tmpA & ctx)
  float* kv = cbuf + (size_t)Tc * 2048;           // Tc*576

  dim3 blk(256);

  for (int t0 = 0; t0 < T; t0 += Tc) {
    const float* x_c = x + (size_t)t0 * 2048;
    // G1: tmpA = x_c @ wq_a
    gemm_f32<<<dim3(1536 / 64, Tc / 64), blk, 0, stream>>>(x_c, wq_a, cbuf, Tc,
                                                           1536, 2048, 2048);
    rmsnorm_inplace<<<Tc, blk, 0, stream>>>(cbuf, q_norm_w, 1536, 1536);
    // G2: q = tmpA @ wq_b
    gemm_f32<<<dim3(3072 / 64, Tc / 64), blk, 0, stream>>>(cbuf, wq_b, q_buf,
                                                           Tc, 3072, 1536,
                                                           1536);
    rope_q<<<(Tc * 16 * 32) / 256, blk, 0, stream>>>(q_buf, start_pos, t0);
    // G3: kv = x_c @ wkv_a
    gemm_f32<<<dim3(576 / 64, Tc / 64), blk, 0, stream>>>(x_c, wkv_a, kv, Tc,
                                                          576, 2048, 2048);
    rope_kpe<<<(Tc * 32) / 256, blk, 0, stream>>>(kv, start_pos);
    rmsnorm_inplace<<<Tc, blk, 0, stream>>>(kv, nullptr, 512, 576);
    // G4: kvup = kvn @ wkv_b   (A has lda=576)
    gemm_f32<<<dim3(4096 / 64, Tc / 64), blk, 0, stream>>>(kv, wkv_b, kvup, Tc,
                                                           4096, 512, 576);
    // attention -> ctx (reuses tmpA slot)
    attn_per_token<<<Tc, blk, 0, stream>>>(q_buf, kvup, kv, cbuf);
    // G5: out_c = ctx @ wo
    gemm_f32<<<dim3(2048 / 64, Tc / 64), blk, 0, stream>>>(
        cbuf, wo, out + (size_t)t0 * 2048, Tc, 2048, 2048, 2048);
  }
}

// Round 3
// 1431.078 us; speedup vs baseline: 6.0789x; 6.0789x over previous
//
#include <hip/hip_runtime.h>
#include <hip/hip_bf16.h>
#include <math.h>

// ---------------------------------------------------------------------------
// MLA forward, bf16-MFMA version (m97 structure).
//   prep: cast+transpose all weights to bf16 W^T[N][K] in ws (wkv_a padded
//         576->640 rows with zeros); cast x chunk to bf16.
//   G1: q_lora = xb @ wq_a^T          (Tc x 2048 x 1536)  bf16 out
//   rmsnorm(q_lora, q_norm_w)
//   G2: q = q_lora @ wq_b^T           (Tc x 1536 x 3072)  bf16 out
//   rope q[...,128:192], pos = ((s*16+h)%4096)+start_pos (bug-compatible)
//   G3: kv = xb @ wkv_a^T             (Tc x 2048 x 576)   bf16 out
//   rope k_pe (pos=start_pos), rmsnorm(kv[:512]) stride 576
//   G4: kvup = kvn @ wkv_b^T          (Tc x 512 x 4096)   bf16 out
//   attention per token (16 heads at same position) -> ctx bf16
//   G5: out = ctx @ wo^T              (Tc x 2048 x 2048)  fp32 out
// ---------------------------------------------------------------------------

typedef __attribute__((ext_vector_type(8))) short short8;
typedef __attribute__((ext_vector_type(4))) float floatx4;

// -------------------- bf16 MFMA GEMM, B transposed -------------------------
// C[M][Nreal] (ld ldc) = A[M][K] (ld lda, bf16) x Bt[Npad][K] (ld K, bf16)^T
// M % 128 == 0, Npad % 128 == 0, K % 32 == 0. Stores masked to col < Nreal.
template <bool OUT_BF16>
__global__ __launch_bounds__(256) void gemm_bf16_bt(
    const __hip_bfloat16* __restrict__ A, const __hip_bfloat16* __restrict__ Bt,
    void* __restrict__ C, int Nreal, int ldc, int K, int lda) {
  __shared__ __hip_bfloat16 As[128 * 32];
  __shared__ __hip_bfloat16 Bs[128 * 32];
  const int tid = threadIdx.x;
  const int lane = tid & 63;
  const int wave = tid >> 6;
  const int wm = wave & 1;   // wave row within 2x2 wave grid
  const int wn = wave >> 1;  // wave col
  const int m0 = blockIdx.y * 128;
  const int n0 = blockIdx.x * 128;

  floatx4 acc[4][4] = {};

  // staging: lane l covers row l/4 (within a 16-row group), bytes (l%4)*16
  const int srow = lane >> 2;
  const int scol = (lane & 3) * 8;  // element offset (8 bf16 = 16B)
  const int r16 = lane & 15;
  const int q8 = (lane >> 4) * 8;

  for (int kt = 0; kt < K; kt += 32) {
    __syncthreads();  // previous iteration's reads done before overwrite
#pragma unroll
    for (int i = 0; i < 2; i++) {
      const int row = i * 64 + wave * 16 + srow;  // LDS dest = base + lane*16
      const __hip_bfloat16* ga = A + (size_t)(m0 + row) * lda + kt + scol;
      __builtin_amdgcn_global_load_lds(
          (const __attribute__((address_space(1))) void*)ga,
          (__attribute__((address_space(3))) void*)(As + row * 32 + scol), 16,
          0, 0);
      const __hip_bfloat16* gb = Bt + (size_t)(n0 + row) * K + kt + scol;
      __builtin_amdgcn_global_load_lds(
          (const __attribute__((address_space(1))) void*)gb,
          (__attribute__((address_space(3))) void*)(Bs + row * 32 + scol), 16,
          0, 0);
    }
    __syncthreads();  // drains vmcnt (staging complete)

    short8 a[4], b[4];
#pragma unroll
    for (int t = 0; t < 4; t++)
      a[t] = *(const short8*)(As + (wm * 64 + t * 16 + r16) * 32 + q8);
#pragma unroll
    for (int t = 0; t < 4; t++)
      b[t] = *(const short8*)(Bs + (wn * 64 + t * 16 + r16) * 32 + q8);
#pragma unroll
    for (int i = 0; i < 4; i++)
#pragma unroll
      for (int j = 0; j < 4; j++)
        acc[i][j] =
            __builtin_amdgcn_mfma_f32_16x16x32_bf16(a[i], b[j], acc[i][j], 0, 0, 0);
  }

  // epilogue: C/D layout col=lane&15, row=(lane>>4)*4+reg (m89-verified)
  const int ccol = lane & 15;
  const int crow = (lane >> 4) * 4;
#pragma unroll
  for (int i = 0; i < 4; i++) {
#pragma unroll
    for (int j = 0; j < 4; j++) {
      const int col = n0 + wn * 64 + j * 16 + ccol;
      if (col < Nreal) {
#pragma unroll
        for (int r = 0; r < 4; r++) {
          const size_t row = m0 + wm * 64 + i * 16 + crow + r;
          if (OUT_BF16)
            ((__hip_bfloat16*)C)[row * ldc + col] = __float2bfloat16(acc[i][j][r]);
          else
            ((float*)C)[row * ldc + col] = acc[i][j][r];
        }
      }
    }
  }
}

// -------------------- weight transpose + cast ------------------------------
// in: f32 [K][N] row-major -> out: bf16 [Npad][K] row-major, zero pad n>=N.
__global__ __launch_bounds__(256) void transpose_cast(
    const float* __restrict__ in, __hip_bfloat16* __restrict__ out, int K,
    int N) {
  __shared__ float tile[32][33];
  const int n0 = blockIdx.x * 32, k0 = blockIdx.y * 32;
  const int tx = threadIdx.x & 31, ty = threadIdx.x >> 5;  // ty 0..7
#pragma unroll
  for (int r = 0; r < 32; r += 8) {
    const int k = k0 + ty + r, n = n0 + tx;
    tile[ty + r][tx] = (n < N) ? in[(size_t)k * N + n] : 0.f;
  }
  __syncthreads();
#pragma unroll
  for (int r = 0; r < 32; r += 8) {
    const int n = n0 + ty + r, k = k0 + tx;
    out[(size_t)n * K + k] = __float2bfloat16(tile[tx][ty + r]);
  }
}

// -------------------- x cast ----------------------------------------------
__global__ __launch_bounds__(256) void cast_f32_bf16(
    const float* __restrict__ in, __hip_bfloat16* __restrict__ out) {
  const size_t i = ((size_t)blockIdx.x * 256 + threadIdx.x) * 4;
  const float4 v = *(const float4*)(in + i);
  out[i + 0] = __float2bfloat16(v.x);
  out[i + 1] = __float2bfloat16(v.y);
  out[i + 2] = __float2bfloat16(v.z);
  out[i + 3] = __float2bfloat16(v.w);
}

// -------------------- RMSNorm (bf16 in-place) ------------------------------
__global__ __launch_bounds__(256) void rmsnorm_bf16(
    __hip_bfloat16* __restrict__ x, const float* __restrict__ w, int ncols,
    int stride) {
  __hip_bfloat16* xr = x + (size_t)blockIdx.x * stride;
  float ss = 0.f;
  for (int c = threadIdx.x; c < ncols; c += 256) {
    const float v = __bfloat162float(xr[c]);
    ss += v * v;
  }
#pragma unroll
  for (int off = 32; off > 0; off >>= 1) ss += __shfl_down(ss, off);
  __shared__ float wsum[4];
  __shared__ float scale_sh;
  const int wv = threadIdx.x >> 6, lane = threadIdx.x & 63;
  if (lane == 0) wsum[wv] = ss;
  __syncthreads();
  if (threadIdx.x == 0) {
    const float tot = wsum[0] + wsum[1] + wsum[2] + wsum[3];
    scale_sh = rsqrtf(tot / (float)ncols + 1e-6f);
  }
  __syncthreads();
  const float scale = scale_sh;
  for (int c = threadIdx.x; c < ncols; c += 256) {
    float v = __bfloat162float(xr[c]) * scale;
    if (w) v *= w[c];
    xr[c] = __float2bfloat16(v);
  }
}

// -------------------- RoPE on q (bug-compatible positions) -----------------
__global__ __launch_bounds__(256) void rope_q_bf16(
    __hip_bfloat16* __restrict__ q, const int* __restrict__ start_pos_p,
    int t0) {
  const int idx = blockIdx.x * 256 + threadIdx.x;  // Tc*16*32
  const int i = idx & 31;
  const int th = idx >> 5;
  const int t = th >> 4;
  const int h = th & 15;
  const int s_idx = (t0 + t) & 4095;
  const int pos = ((s_idx * 16 + h) & 4095) + start_pos_p[0];
  const double theta = pow(10000.0, -(double)i / 32.0);
  const double ang = (double)pos * theta;
  const float c = (float)cos(ang), s = (float)sin(ang);
  __hip_bfloat16* base = q + (size_t)t * 3072 + h * 192 + 128;
  const float x1 = __bfloat162float(base[i]);
  const float x2 = __bfloat162float(base[i + 32]);
  base[i] = __float2bfloat16(x1 * c - x2 * s);
  base[i + 32] = __float2bfloat16(x2 * c + x1 * s);
}

// -------------------- RoPE on k_pe (pos = start_pos) -----------------------
__global__ __launch_bounds__(256) void rope_kpe_bf16(
    __hip_bfloat16* __restrict__ kv, const int* __restrict__ start_pos_p) {
  const int idx = blockIdx.x * 256 + threadIdx.x;  // Tc*32
  const int i = idx & 31;
  const int t = idx >> 5;
  const int pos = start_pos_p[0];
  const double theta = pow(10000.0, -(double)i / 32.0);
  const double ang = (double)pos * theta;
  const float c = (float)cos(ang), s = (float)sin(ang);
  __hip_bfloat16* base = kv + (size_t)t * 576 + 512;
  const float x1 = __bfloat162float(base[i]);
  const float x2 = __bfloat162float(base[i + 32]);
  base[i] = __float2bfloat16(x1 * c - x2 * s);
  base[i + 32] = __float2bfloat16(x2 * c + x1 * s);
}

// -------------------- per-token head-vs-head attention ---------------------
__global__ __launch_bounds__(256) void attn_per_token(
    const __hip_bfloat16* __restrict__ q,     // [Tc][16][192]
    const __hip_bfloat16* __restrict__ kvup,  // [Tc][16][256] (k_nope|v)
    const __hip_bfloat16* __restrict__ kv,    // [Tc][576], k_pe at +512
    __hip_bfloat16* __restrict__ ctx) {       // [Tc][16][128]
  const int t = blockIdx.x;
  __shared__ float sq[16 * 192];
  __shared__ float sk[16 * 128];
  __shared__ float skpe[64];
  __shared__ float sv[16 * 128];
  __shared__ float sc[16][16];
  __shared__ float sprob[16][16];
  const int tid = threadIdx.x;
  const __hip_bfloat16* qb = q + (size_t)t * 3072;
  const __hip_bfloat16* ub = kvup + (size_t)t * 4096;
  for (int i = tid; i < 3072; i += 256) sq[i] = __bfloat162float(qb[i]);
  for (int i = tid; i < 2048; i += 256) {
    const int hh = i >> 7, d = i & 127;
    sk[i] = __bfloat162float(ub[hh * 256 + d]);
    sv[i] = __bfloat162float(ub[hh * 256 + 128 + d]);
  }
  if (tid < 64) skpe[tid] = __bfloat162float(kv[(size_t)t * 576 + 512 + tid]);
  __syncthreads();

  const int qh = tid >> 4, kh = tid & 15;
  const float* qq = sq + qh * 192;
  const float* kk = sk + kh * 128;
  float acc = 0.f;
#pragma unroll 4
  for (int d = 0; d < 128; d++) acc += qq[d] * kk[d];
#pragma unroll 4
  for (int d = 0; d < 64; d++) acc += qq[128 + d] * skpe[d];
  sc[qh][kh] = acc * 0.07216878364870323f;  // 1/sqrt(192)
  __syncthreads();

  if (tid < 16) {
    float m = sc[tid][0];
#pragma unroll
    for (int j = 1; j < 16; j++) m = fmaxf(m, sc[tid][j]);
    float e[16], ssum = 0.f;
#pragma unroll
    for (int j = 0; j < 16; j++) {
      e[j] = expf(sc[tid][j] - m);
      ssum += e[j];
    }
    const float inv = 1.0f / ssum;
#pragma unroll
    for (int j = 0; j < 16; j++) sprob[tid][j] = e[j] * inv;
  }
  __syncthreads();

  __hip_bfloat16* cb = ctx + (size_t)t * 2048;
  for (int o = tid; o < 2048; o += 256) {
    const int hh = o >> 7, d = o & 127;
    float a = 0.f;
#pragma unroll
    for (int j = 0; j < 16; j++) a += sprob[hh][j] * sv[j * 128 + d];
    cb[o] = __float2bfloat16(a);
  }
}

// ---------------------------------------------------------------------------
extern "C" void kernel_launch(void* const* d_in, const int* in_sizes, int n_in,
                              void* d_out, int out_size, void* d_ws,
                              size_t ws_size, hipStream_t stream) {
  const float* x = (const float*)d_in[0];          // 16384 x 2048
  const float* wq_a = (const float*)d_in[1];       // 2048 x 1536
  const float* q_norm_w = (const float*)d_in[2];   // 1536
  const float* wq_b = (const float*)d_in[3];       // 1536 x 3072
  const float* wkv_a = (const float*)d_in[4];      // 2048 x 576
  const float* wkv_b = (const float*)d_in[5];      // 512 x 4096
  const float* wo = (const float*)d_in[6];         // 2048 x 2048
  const int* start_pos = (const int*)d_in[7];
  float* out = (float*)d_out;

  const int T = 16384;
  // persistent bf16 transposed weights
  __hip_bfloat16* w0 = (__hip_bfloat16*)d_ws;
  __hip_bfloat16* wq_aT = w0;                        // 1536 x 2048
  __hip_bfloat16* wq_bT = wq_aT + 1536 * 2048;       // 3072 x 1536
  __hip_bfloat16* wkv_aT = wq_bT + 3072 * 1536;      // 640 x 2048 (padded)
  __hip_bfloat16* wkv_bT = wkv_aT + 640 * 2048;      // 4096 x 512
  __hip_bfloat16* woT = wkv_bT + 4096 * 512;         // 2048 x 2048
  __hip_bfloat16* chunk0 = woT + 2048 * 2048;
  const size_t w_bytes = (size_t)(chunk0 - w0) * sizeof(__hip_bfloat16);

  // per-token chunk scratch (bf16): xb 2048 + q 3072 + kvup 4096 + cbuf 2048
  // (q_lora & ctx) + kv 576  = 11840 elems = 23680 B
  const size_t per_tok = 11840 * sizeof(__hip_bfloat16);
  int Tc = T;
  while (Tc > 128 && w_bytes + (size_t)Tc * per_tok > ws_size) Tc >>= 1;

  __hip_bfloat16* xb = chunk0;                       // Tc x 2048
  __hip_bfloat16* q_buf = xb + (size_t)Tc * 2048;    // Tc x 3072
  __hip_bfloat16* kvup = q_buf + (size_t)Tc * 3072;  // Tc x 4096
  __hip_bfloat16* cbuf = kvup + (size_t)Tc * 4096;   // Tc x 2048
  __hip_bfloat16* kv = cbuf + (size_t)Tc * 2048;     // Tc x 576

  dim3 blk(256);

  // weight prep (every call: ws is re-poisoned before each timed launch)
  transpose_cast<<<dim3(1536 / 32, 2048 / 32), blk, 0, stream>>>(wq_a, wq_aT,
                                                                 2048, 1536);
  transpose_cast<<<dim3(3072 / 32, 1536 / 32), blk, 0, stream>>>(wq_b, wq_bT,
                                                                 1536, 3072);
  transpose_cast<<<dim3(640 / 32, 2048 / 32), blk, 0, stream>>>(wkv_a, wkv_aT,
                                                                2048, 576);
  transpose_cast<<<dim3(4096 / 32, 512 / 32), blk, 0, stream>>>(wkv_b, wkv_bT,
                                                                512, 4096);
  transpose_cast<<<dim3(2048 / 32, 2048 / 32), blk, 0, stream>>>(wo, woT, 2048,
                                                                 2048);

  for (int t0 = 0; t0 < T; t0 += Tc) {
    // cast x chunk
    cast_f32_bf16<<<(Tc * 2048) / 1024, blk, 0, stream>>>(
        x + (size_t)t0 * 2048, xb);
    // G1: q_lora = xb @ wq_a^T -> cbuf (ld 1536)
    gemm_bf16_bt<true><<<dim3(1536 / 128, Tc / 128), blk, 0, stream>>>(
        xb, wq_aT, cbuf, 1536, 1536, 2048, 2048);
    rmsnorm_bf16<<<Tc, blk, 0, stream>>>(cbuf, q_norm_w, 1536, 1536);
    // G2: q = q_lora @ wq_b^T
    gemm_bf16_bt<true><<<dim3(3072 / 128, Tc / 128), blk, 0, stream>>>(
        cbuf, wq_bT, q_buf, 3072, 3072, 1536, 1536);
    rope_q_bf16<<<(Tc * 16 * 32) / 256, blk, 0, stream>>>(q_buf, start_pos, t0);
    // G3: kv = xb @ wkv_a^T (Npad=640, store masked to 576)
    gemm_bf16_bt<true><<<dim3(640 / 128, Tc / 128), blk, 0, stream>>>(
        xb, wkv_aT, kv, 576, 576, 2048, 2048);
    rope_kpe_bf16<<<(Tc * 32) / 256, blk, 0, stream>>>(kv, start_pos);
    rmsnorm_bf16<<<Tc, blk, 0, stream>>>(kv, nullptr, 512, 576);
    // G4: kvup = kvn @ wkv_b^T (A ld 576, K=512)
    gemm_bf16_bt<true><<<dim3(4096 / 128, Tc / 128), blk, 0, stream>>>(
        kv, wkv_bT, kvup, 4096, 4096, 512, 576);
    // attention -> ctx (reuses cbuf)
    attn_per_token<<<Tc, blk, 0, stream>>>(q_buf, kvup, kv, cbuf);
    // G5: out = ctx @ wo^T (fp32 out)
    gemm_bf16_bt<false><<<dim3(2048 / 128, Tc / 128), blk, 0, stream>>>(
        cbuf, woT, out + (size_t)t0 * 2048, 2048, 2048, 2048, 2048);
  }
}

// Round 4
// 1194.983 us; speedup vs baseline: 7.2799x; 1.1976x over previous
//
#include <hip/hip_runtime.h>
#include <hip/hip_bf16.h>
#include <math.h>

// ---------------------------------------------------------------------------
// MLA forward, bf16-MFMA GEMMs + wave-per-token attention.
// ---------------------------------------------------------------------------

typedef __attribute__((ext_vector_type(8))) short short8;
typedef __attribute__((ext_vector_type(4))) short short4x;
typedef __attribute__((ext_vector_type(4))) float floatx4;

__device__ inline float bfbits2f(unsigned short u) {
  union { unsigned int i; float f; } c;
  c.i = ((unsigned int)u) << 16;
  return c.f;
}

// -------------------- bf16 MFMA GEMM, B transposed -------------------------
// C[M][Nreal] (ld ldc) = A[M][K] (ld lda, bf16) x Bt[Npad][K] (ld K, bf16)^T
// M % 128 == 0, Npad % 128 == 0, K % 32 == 0. Stores masked to col < Nreal.
template <bool OUT_BF16>
__global__ __launch_bounds__(256) void gemm_bf16_bt(
    const __hip_bfloat16* __restrict__ A, const __hip_bfloat16* __restrict__ Bt,
    void* __restrict__ C, int Nreal, int ldc, int K, int lda) {
  __shared__ __hip_bfloat16 As[128 * 32];
  __shared__ __hip_bfloat16 Bs[128 * 32];
  const int tid = threadIdx.x;
  const int lane = tid & 63;
  const int wave = tid >> 6;
  const int wm = wave & 1;
  const int wn = wave >> 1;
  const int m0 = blockIdx.y * 128;
  const int n0 = blockIdx.x * 128;

  floatx4 acc[4][4] = {};

  const int srow = lane >> 2;
  const int scol = (lane & 3) * 8;  // element offset (8 bf16 = 16B)
  const int r16 = lane & 15;
  const int q8 = (lane >> 4) * 8;

  for (int kt = 0; kt < K; kt += 32) {
    __syncthreads();
#pragma unroll
    for (int i = 0; i < 2; i++) {
      const int row = i * 64 + wave * 16 + srow;
      const __hip_bfloat16* ga = A + (size_t)(m0 + row) * lda + kt + scol;
      __builtin_amdgcn_global_load_lds(
          (const __attribute__((address_space(1))) void*)ga,
          (__attribute__((address_space(3))) void*)(As + row * 32 + scol), 16,
          0, 0);
      const __hip_bfloat16* gb = Bt + (size_t)(n0 + row) * K + kt + scol;
      __builtin_amdgcn_global_load_lds(
          (const __attribute__((address_space(1))) void*)gb,
          (__attribute__((address_space(3))) void*)(Bs + row * 32 + scol), 16,
          0, 0);
    }
    __syncthreads();

    short8 a[4], b[4];
#pragma unroll
    for (int t = 0; t < 4; t++)
      a[t] = *(const short8*)(As + (wm * 64 + t * 16 + r16) * 32 + q8);
#pragma unroll
    for (int t = 0; t < 4; t++)
      b[t] = *(const short8*)(Bs + (wn * 64 + t * 16 + r16) * 32 + q8);
#pragma unroll
    for (int i = 0; i < 4; i++)
#pragma unroll
      for (int j = 0; j < 4; j++)
        acc[i][j] = __builtin_amdgcn_mfma_f32_16x16x32_bf16(a[i], b[j],
                                                            acc[i][j], 0, 0, 0);
  }

  const int ccol = lane & 15;
  const int crow = (lane >> 4) * 4;
#pragma unroll
  for (int i = 0; i < 4; i++) {
#pragma unroll
    for (int j = 0; j < 4; j++) {
      const int col = n0 + wn * 64 + j * 16 + ccol;
      if (col < Nreal) {
#pragma unroll
        for (int r = 0; r < 4; r++) {
          const size_t row = m0 + wm * 64 + i * 16 + crow + r;
          if (OUT_BF16)
            ((__hip_bfloat16*)C)[row * ldc + col] =
                __float2bfloat16(acc[i][j][r]);
          else
            ((float*)C)[row * ldc + col] = acc[i][j][r];
        }
      }
    }
  }
}

// -------------------- weight transpose + cast ------------------------------
__global__ __launch_bounds__(256) void transpose_cast(
    const float* __restrict__ in, __hip_bfloat16* __restrict__ out, int K,
    int N) {
  __shared__ float tile[32][33];
  const int n0 = blockIdx.x * 32, k0 = blockIdx.y * 32;
  const int tx = threadIdx.x & 31, ty = threadIdx.x >> 5;
#pragma unroll
  for (int r = 0; r < 32; r += 8) {
    const int k = k0 + ty + r, n = n0 + tx;
    tile[ty + r][tx] = (n < N) ? in[(size_t)k * N + n] : 0.f;
  }
  __syncthreads();
#pragma unroll
  for (int r = 0; r < 32; r += 8) {
    const int n = n0 + ty + r, k = k0 + tx;
    out[(size_t)n * K + k] = __float2bfloat16(tile[tx][ty + r]);
  }
}

// -------------------- x cast ----------------------------------------------
__global__ __launch_bounds__(256) void cast_f32_bf16(
    const float* __restrict__ in, __hip_bfloat16* __restrict__ out) {
  const size_t i = ((size_t)blockIdx.x * 256 + threadIdx.x) * 4;
  const float4 v = *(const float4*)(in + i);
  out[i + 0] = __float2bfloat16(v.x);
  out[i + 1] = __float2bfloat16(v.y);
  out[i + 2] = __float2bfloat16(v.z);
  out[i + 3] = __float2bfloat16(v.w);
}

// -------------------- RMSNorm (bf16 in-place, short8 vectorized) -----------
__global__ __launch_bounds__(256) void rmsnorm_bf16(
    __hip_bfloat16* __restrict__ x, const float* __restrict__ w, int ncols,
    int stride) {
  __hip_bfloat16* xr = x + (size_t)blockIdx.x * stride;
  float ss = 0.f;
  for (int c = threadIdx.x * 8; c < ncols; c += 2048) {
    const short8 v = *(const short8*)(xr + c);
#pragma unroll
    for (int k = 0; k < 8; k++) {
      const float f = bfbits2f((unsigned short)v[k]);
      ss += f * f;
    }
  }
#pragma unroll
  for (int off = 32; off > 0; off >>= 1) ss += __shfl_down(ss, off);
  __shared__ float wsum[4];
  __shared__ float scale_sh;
  const int wv = threadIdx.x >> 6, lane = threadIdx.x & 63;
  if (lane == 0) wsum[wv] = ss;
  __syncthreads();
  if (threadIdx.x == 0) {
    const float tot = wsum[0] + wsum[1] + wsum[2] + wsum[3];
    scale_sh = rsqrtf(tot / (float)ncols + 1e-6f);
  }
  __syncthreads();
  const float scale = scale_sh;
  for (int c = threadIdx.x * 8; c < ncols; c += 2048) {
    const short8 v = *(const short8*)(xr + c);
    short8 o;
#pragma unroll
    for (int k = 0; k < 8; k++) {
      float f = bfbits2f((unsigned short)v[k]) * scale;
      if (w) f *= w[c + k];
      const __hip_bfloat16 b = __float2bfloat16(f);
      o[k] = *(const short*)&b;
    }
    *(short8*)(xr + c) = o;
  }
}

// -------------------- RoPE on q (bug-compatible positions) -----------------
__global__ __launch_bounds__(256) void rope_q_bf16(
    __hip_bfloat16* __restrict__ q, const int* __restrict__ start_pos_p,
    int t0) {
  const int idx = blockIdx.x * 256 + threadIdx.x;  // Tc*16*32
  const int i = idx & 31;
  const int th = idx >> 5;
  const int t = th >> 4;
  const int h = th & 15;
  const int s_idx = (t0 + t) & 4095;
  const int pos = ((s_idx * 16 + h) & 4095) + start_pos_p[0];
  const double theta = pow(10000.0, -(double)i / 32.0);
  const double ang = (double)pos * theta;
  const float c = (float)cos(ang), s = (float)sin(ang);
  __hip_bfloat16* base = q + (size_t)t * 3072 + h * 192 + 128;
  const float x1 = __bfloat162float(base[i]);
  const float x2 = __bfloat162float(base[i + 32]);
  base[i] = __float2bfloat16(x1 * c - x2 * s);
  base[i + 32] = __float2bfloat16(x2 * c + x1 * s);
}

// -------------------- RoPE on k_pe (pos = start_pos) -----------------------
__global__ __launch_bounds__(256) void rope_kpe_bf16(
    __hip_bfloat16* __restrict__ kv, const int* __restrict__ start_pos_p) {
  const int idx = blockIdx.x * 256 + threadIdx.x;  // Tc*32
  const int i = idx & 31;
  const int t = idx >> 5;
  const int pos = start_pos_p[0];
  const double theta = pow(10000.0, -(double)i / 32.0);
  const double ang = (double)pos * theta;
  const float c = (float)cos(ang), s = (float)sin(ang);
  __hip_bfloat16* base = kv + (size_t)t * 576 + 512;
  const float x1 = __bfloat162float(base[i]);
  const float x2 = __bfloat162float(base[i + 32]);
  base[i] = __float2bfloat16(x1 * c - x2 * s);
  base[i + 32] = __float2bfloat16(x2 * c + x1 * s);
}

// -------------------- wave-per-token attention -----------------------------
// 4 tokens per block (one wave each). Coalesced short8 staging into padded
// LDS (q rows 192->200, kvup rows 256->264: conflict-free strides).
// Score pairs: lane -> qh = lane>>2, kh = (lane&3)+4p, p=0..3.
// Softmax via shfl_xor(1,2) over the 4-lane row group. PV with V in regs.
__global__ __launch_bounds__(256) void attn_wave_token(
    const __hip_bfloat16* __restrict__ q,     // [T][16][192]
    const __hip_bfloat16* __restrict__ kvup,  // [T][16][256] (k_nope|v)
    const __hip_bfloat16* __restrict__ kv,    // [T][576], k_pe at +512
    __hip_bfloat16* __restrict__ ctx) {       // [T][16][128]
  __shared__ __hip_bfloat16 sq[4][16 * 200];
  __shared__ __hip_bfloat16 su[4][16 * 264];
  __shared__ __hip_bfloat16 skpe[4][64];
  __shared__ float sp[4][16][16];
  const int tid = threadIdx.x;
  const int w = tid >> 6;
  const int lane = tid & 63;
  const int t = blockIdx.x * 4 + w;

  // ---- stage (perfectly coalesced: global addr = base + 8*u elements) ----
  const __hip_bfloat16* qb = q + (size_t)t * 3072;
  const __hip_bfloat16* ub = kvup + (size_t)t * 4096;
#pragma unroll
  for (int i = 0; i < 6; i++) {
    const int u = lane + 64 * i;  // u < 384
    const int row = u / 24;
    *(short8*)(&sq[w][u * 8 + row * 8]) = *(const short8*)(qb + u * 8);
  }
#pragma unroll
  for (int i = 0; i < 8; i++) {
    const int u = lane + 64 * i;  // u < 512
    const int row = u >> 5;
    *(short8*)(&su[w][u * 8 + row * 8]) = *(const short8*)(ub + u * 8);
  }
  if (lane < 8)
    *(short8*)(&skpe[w][lane * 8]) =
        *(const short8*)(kv + (size_t)t * 576 + 512 + lane * 8);
  __syncthreads();

  // ---- scores: s[p] = q[qh] . k[(lane&3)+4p], len 192 ----
  const int qh = lane >> 2;
  const int khb = lane & 3;
  float s[4] = {0.f, 0.f, 0.f, 0.f};
  // d = 0..127 from kvup k_nope
#pragma unroll
  for (int c = 0; c < 128; c += 8) {
    const short8 qv = *(const short8*)(&sq[w][qh * 200 + c]);
    float qf[8];
#pragma unroll
    for (int k = 0; k < 8; k++) qf[k] = bfbits2f((unsigned short)qv[k]);
#pragma unroll
    for (int p = 0; p < 4; p++) {
      const short8 kvv = *(const short8*)(&su[w][(khb + 4 * p) * 264 + c]);
#pragma unroll
      for (int k = 0; k < 8; k++)
        s[p] += qf[k] * bfbits2f((unsigned short)kvv[k]);
    }
  }
  // d = 128..191 from shared k_pe (same for all kh)
#pragma unroll
  for (int c = 0; c < 64; c += 8) {
    const short8 qv = *(const short8*)(&sq[w][qh * 200 + 128 + c]);
    const short8 kvv = *(const short8*)(&skpe[w][c]);
#pragma unroll
    for (int k = 0; k < 8; k++) {
      const float prod =
          bfbits2f((unsigned short)qv[k]) * bfbits2f((unsigned short)kvv[k]);
#pragma unroll
      for (int p = 0; p < 4; p++) s[p] += prod;
    }
  }
  const float scale = 0.07216878364870323f;  // 1/sqrt(192)
#pragma unroll
  for (int p = 0; p < 4; p++) s[p] *= scale;

  // ---- softmax over kh (row qh lives in lanes 4qh..4qh+3, 4 vals each) ----
  float mx = fmaxf(fmaxf(s[0], s[1]), fmaxf(s[2], s[3]));
  mx = fmaxf(mx, __shfl_xor(mx, 1));
  mx = fmaxf(mx, __shfl_xor(mx, 2));
  float e[4], sum = 0.f;
#pragma unroll
  for (int p = 0; p < 4; p++) {
    e[p] = expf(s[p] - mx);
    sum += e[p];
  }
  sum += __shfl_xor(sum, 1);
  sum += __shfl_xor(sum, 2);
  const float inv = 1.0f / sum;
#pragma unroll
  for (int p = 0; p < 4; p++) sp[w][qh][khb + 4 * p] = e[p] * inv;
  __syncthreads();

  // ---- PV: ctx[hh][d0..d0+3] = sum_j p[hh][j] * v[j][d0..d0+3] ----
  const int d0 = (lane & 31) * 4;
  float vreg[16][4];
#pragma unroll
  for (int j = 0; j < 16; j++) {
    const short4x v4 = *(const short4x*)(&su[w][j * 264 + 128 + d0]);
#pragma unroll
    for (int k = 0; k < 4; k++) vreg[j][k] = bfbits2f((unsigned short)v4[k]);
  }
  const int hb = (lane >> 5) * 8;
  __hip_bfloat16* cb = ctx + (size_t)t * 2048;
#pragma unroll
  for (int g = 0; g < 8; g++) {
    const int hh = hb + g;
    float o[4] = {0.f, 0.f, 0.f, 0.f};
#pragma unroll
    for (int j4 = 0; j4 < 4; j4++) {
      const float4 p4 = *(const float4*)(&sp[w][hh][j4 * 4]);
      const float pj[4] = {p4.x, p4.y, p4.z, p4.w};
#pragma unroll
      for (int jj = 0; jj < 4; jj++) {
        const int j = j4 * 4 + jj;
#pragma unroll
        for (int k = 0; k < 4; k++) o[k] += pj[jj] * vreg[j][k];
      }
    }
    short4x st;
#pragma unroll
    for (int k = 0; k < 4; k++) {
      const __hip_bfloat16 b = __float2bfloat16(o[k]);
      st[k] = *(const short*)&b;
    }
    *(short4x*)(cb + hh * 128 + d0) = st;
  }
}

// ---------------------------------------------------------------------------
extern "C" void kernel_launch(void* const* d_in, const int* in_sizes, int n_in,
                              void* d_out, int out_size, void* d_ws,
                              size_t ws_size, hipStream_t stream) {
  const float* x = (const float*)d_in[0];          // 16384 x 2048
  const float* wq_a = (const float*)d_in[1];       // 2048 x 1536
  const float* q_norm_w = (const float*)d_in[2];   // 1536
  const float* wq_b = (const float*)d_in[3];       // 1536 x 3072
  const float* wkv_a = (const float*)d_in[4];      // 2048 x 576
  const float* wkv_b = (const float*)d_in[5];      // 512 x 4096
  const float* wo = (const float*)d_in[6];         // 2048 x 2048
  const int* start_pos = (const int*)d_in[7];
  float* out = (float*)d_out;

  const int T = 16384;
  __hip_bfloat16* w0 = (__hip_bfloat16*)d_ws;
  __hip_bfloat16* wq_aT = w0;                        // 1536 x 2048
  __hip_bfloat16* wq_bT = wq_aT + 1536 * 2048;       // 3072 x 1536
  __hip_bfloat16* wkv_aT = wq_bT + 3072 * 1536;      // 640 x 2048 (padded)
  __hip_bfloat16* wkv_bT = wkv_aT + 640 * 2048;      // 4096 x 512
  __hip_bfloat16* woT = wkv_bT + 4096 * 512;         // 2048 x 2048
  __hip_bfloat16* chunk0 = woT + 2048 * 2048;
  const size_t w_bytes = (size_t)(chunk0 - w0) * sizeof(__hip_bfloat16);

  const size_t per_tok = 11840 * sizeof(__hip_bfloat16);
  int Tc = T;
  while (Tc > 128 && w_bytes + (size_t)Tc * per_tok > ws_size) Tc >>= 1;

  __hip_bfloat16* xb = chunk0;                       // Tc x 2048
  __hip_bfloat16* q_buf = xb + (size_t)Tc * 2048;    // Tc x 3072
  __hip_bfloat16* kvup = q_buf + (size_t)Tc * 3072;  // Tc x 4096
  __hip_bfloat16* cbuf = kvup + (size_t)Tc * 4096;   // Tc x 2048
  __hip_bfloat16* kv = cbuf + (size_t)Tc * 2048;     // Tc x 576

  dim3 blk(256);

  transpose_cast<<<dim3(1536 / 32, 2048 / 32), blk, 0, stream>>>(wq_a, wq_aT,
                                                                 2048, 1536);
  transpose_cast<<<dim3(3072 / 32, 1536 / 32), blk, 0, stream>>>(wq_b, wq_bT,
                                                                 1536, 3072);
  transpose_cast<<<dim3(640 / 32, 2048 / 32), blk, 0, stream>>>(wkv_a, wkv_aT,
                                                                2048, 576);
  transpose_cast<<<dim3(4096 / 32, 512 / 32), blk, 0, stream>>>(wkv_b, wkv_bT,
                                                                512, 4096);
  transpose_cast<<<dim3(2048 / 32, 2048 / 32), blk, 0, stream>>>(wo, woT, 2048,
                                                                 2048);

  for (int t0 = 0; t0 < T; t0 += Tc) {
    cast_f32_bf16<<<(Tc * 2048) / 1024, blk, 0, stream>>>(
        x + (size_t)t0 * 2048, xb);
    // G1: q_lora = xb @ wq_a^T -> cbuf
    gemm_bf16_bt<true><<<dim3(1536 / 128, Tc / 128), blk, 0, stream>>>(
        xb, wq_aT, cbuf, 1536, 1536, 2048, 2048);
    rmsnorm_bf16<<<Tc, blk, 0, stream>>>(cbuf, q_norm_w, 1536, 1536);
    // G2: q = q_lora @ wq_b^T
    gemm_bf16_bt<true><<<dim3(3072 / 128, Tc / 128), blk, 0, stream>>>(
        cbuf, wq_bT, q_buf, 3072, 3072, 1536, 1536);
    rope_q_bf16<<<(Tc * 16 * 32) / 256, blk, 0, stream>>>(q_buf, start_pos, t0);
    // G3: kv = xb @ wkv_a^T (Npad=640, store masked to 576)
    gemm_bf16_bt<true><<<dim3(640 / 128, Tc / 128), blk, 0, stream>>>(
        xb, wkv_aT, kv, 576, 576, 2048, 2048);
    rope_kpe_bf16<<<(Tc * 32) / 256, blk, 0, stream>>>(kv, start_pos);
    rmsnorm_bf16<<<Tc, blk, 0, stream>>>(kv, nullptr, 512, 576);
    // G4: kvup = kvn @ wkv_b^T (A ld 576, K=512)
    gemm_bf16_bt<true><<<dim3(4096 / 128, Tc / 128), blk, 0, stream>>>(
        kv, wkv_bT, kvup, 4096, 4096, 512, 576);
    // attention -> ctx (reuses cbuf)
    attn_wave_token<<<Tc / 4, blk, 0, stream>>>(q_buf, kvup, kv, cbuf);
    // G5: out = ctx @ wo^T (fp32 out)
    gemm_bf16_bt<false><<<dim3(2048 / 128, Tc / 128), blk, 0, stream>>>(
        cbuf, woT, out + (size_t)t0 * 2048, 2048, 2048, 2048, 2048);
  }
}